// Round 11
// baseline (193.513 us; speedup 1.0000x reference)
//
#include <hip/hip_runtime.h>
#include <math.h>

#define BATCH 2
#define SEQ   2048
#define DM    1024
#define DI    2048
#define NST   16
#define MT    (BATCH*SEQ)   // 4096
#define CHK   64            // chunks along T
#define LCH   (SEQ/CHK)     // 32 steps per chunk

typedef __attribute__((ext_vector_type(8))) short  bf16x8;
typedef __attribute__((ext_vector_type(4))) float  f32x4;

static __device__ __forceinline__ unsigned short f2bf(float f) {
  unsigned u = __float_as_uint(f);
  u += 0x7fff + ((u >> 16) & 1);          // RNE
  return (unsigned short)(u >> 16);
}
static __device__ __forceinline__ float bf2f(unsigned short h) {
  return __uint_as_float(((unsigned)h) << 16);
}
static __device__ __forceinline__ float fexp2(float x) {
  float r;
  asm("v_exp_f32 %0, %1" : "=v"(r) : "v"(x));
  return r;
}
static __device__ __forceinline__ float flog2(float x) {
  float r;
  asm("v_log_f32 %0, %1" : "=v"(r) : "v"(x));
  return r;
}

// ---------------------------------------------------------------------------
// Fused fp32->bf16 conversions + A2 table, one launch.
// ---------------------------------------------------------------------------
#define SEG_U    (MT*DM/4)
#define SEG_WIN  (2*DI*DM/4)
#define SEG_WOUT (DM*DI/4)
#define SEG_WX   (96*DI/4)
#define SEG_WDT  (DI*64/4)
#define SEG_A    (DI*NST/4)
#define CUM0 SEG_U
#define CUM1 (CUM0+SEG_WIN)
#define CUM2 (CUM1+SEG_WOUT)
#define CUM3 (CUM2+SEG_WX)
#define CUM4 (CUM3+SEG_WDT)
#define CUM5 (CUM4+SEG_A)

__global__ __launch_bounds__(256) void convall_kernel(
    const float* __restrict__ u, const float* __restrict__ W_in,
    const float* __restrict__ W_out, const float* __restrict__ W_x,
    const float* __restrict__ W_dt, const float* __restrict__ A_log,
    unsigned short* __restrict__ u_bf, unsigned short* __restrict__ win_bf,
    unsigned short* __restrict__ wout_bf, unsigned short* __restrict__ wx_bf,
    unsigned short* __restrict__ wdt_bf, float* __restrict__ A2tab)
{
  const int gid = blockIdx.x*256 + threadIdx.x;
  const float4* src; ushort4* dst; int idx;
  if (gid < CUM0)      { idx = gid;        src = (const float4*)u;     dst = (ushort4*)u_bf; }
  else if (gid < CUM1) { idx = gid - CUM0; src = (const float4*)W_in;  dst = (ushort4*)win_bf; }
  else if (gid < CUM2) { idx = gid - CUM1; src = (const float4*)W_out; dst = (ushort4*)wout_bf; }
  else if (gid < CUM3) { idx = gid - CUM2; src = (const float4*)W_x;   dst = (ushort4*)wx_bf; }
  else if (gid < CUM4) { idx = gid - CUM3; src = (const float4*)W_dt;  dst = (ushort4*)wdt_bf; }
  else if (gid < CUM5) {
    int i = gid - CUM4;
    float4 v = ((const float4*)A_log)[i];
    float4 o;
    o.x = -1.44269504f * __expf(v.x);
    o.y = -1.44269504f * __expf(v.y);
    o.z = -1.44269504f * __expf(v.z);
    o.w = -1.44269504f * __expf(v.w);
    ((float4*)A2tab)[i] = o;
    return;
  } else return;
  float4 v = src[idx];
  ushort4 o;
  o.x = f2bf(v.x); o.y = f2bf(v.y); o.z = f2bf(v.z); o.w = f2bf(v.w);
  dst[idx] = o;
}

// ---------------------------------------------------------------------------
// gemm3: 256x256 tile, BK=32, ring-4 LDS (128 KiB dynamic), 512 thr = 8 waves
// (2M x 4N), wave tile 128x64.  Counted-vmcnt pipeline: tile t staged during
// tile t-3; boundary wait = vmcnt(8).  ONE barrier per tile (boundary) —
// mid-phase barriers removed: slot-disjointness makes them correctness-
// irrelevant, and dropping them lets waves drift so one wave's MFMA overlaps
// another's LDS reads (m114 mechanism).
// ---------------------------------------------------------------------------
#define MEMFENCE asm volatile("" ::: "memory")

template<int K>
__global__ __launch_bounds__(512, 2) void gemm3_kernel(
    const unsigned short* __restrict__ A,
    const unsigned short* __restrict__ B,
    const float* __restrict__ bias,
    unsigned short* __restrict__ Cout, int nbx)
{
  extern __shared__ unsigned short smem[];
  unsigned short* As = smem;                 // [4][256*32]
  unsigned short* Bs = smem + 4*256*32;      // [4][256*32]
  constexpr int NT = K / 32;

  const int nwg = gridDim.x;
  const int cpx = nwg >> 3;
  const int bid = blockIdx.x;
  const int swz = (bid & 7) * cpx + (bid >> 3);
  const int bx = swz % nbx;
  const int by = swz / nbx;

  const int tid  = threadIdx.x;
  const int lane = tid & 63;
  const int wid  = tid >> 6;          // 0..7
  const int wr   = wid >> 2;          // 0..1  (M half)
  const int wc   = wid & 3;           // 0..3  (N quarter)

  const size_t arow0 = (size_t)by * 256;
  const size_t brow0 = (size_t)bx * 256;

  const int s_r4 = lane >> 2;         // 0..15
  const int s_c  = lane & 3;          // chunk 0..3

  auto STAGE_A = [&](int slot, int T) {
#pragma unroll
    for (int i = 0; i < 2; ++i) {
      const int r  = wid*32 + i*16 + s_r4;
      const int lc = s_c ^ ((r >> 1) & 3);
      const unsigned short* g = A + (arow0 + r)*(size_t)K + T*32 + lc*8;
      __builtin_amdgcn_global_load_lds(
          (const __attribute__((address_space(1))) void*)g,
          (__attribute__((address_space(3))) void*)(As + slot*(256*32) + (wid*32 + i*16)*32),
          16, 0, 0);
    }
  };
  auto STAGE_B = [&](int slot, int T) {
#pragma unroll
    for (int i = 0; i < 2; ++i) {
      const int r  = wid*32 + i*16 + s_r4;
      const int lc = s_c ^ ((r >> 1) & 3);
      const unsigned short* g = B + (brow0 + r)*(size_t)K + T*32 + lc*8;
      __builtin_amdgcn_global_load_lds(
          (const __attribute__((address_space(1))) void*)g,
          (__attribute__((address_space(3))) void*)(Bs + slot*(256*32) + (wid*32 + i*16)*32),
          16, 0, 0);
    }
  };

  f32x4 zero = {0.f, 0.f, 0.f, 0.f};
  f32x4 acc[8][4];
#pragma unroll
  for (int i = 0; i < 8; ++i)
#pragma unroll
    for (int j = 0; j < 4; ++j) acc[i][j] = zero;

  // prologue: stage tiles 0,1,2 -> 12 loads/thread in flight
  STAGE_A(0, 0); STAGE_B(0, 0);
  STAGE_A(1, 1); STAGE_B(1, 1);
  STAGE_A(2, 2); STAGE_B(2, 2);
  asm volatile("s_waitcnt vmcnt(8)" ::: "memory");   // tile 0 complete
  __builtin_amdgcn_s_barrier();
  MEMFENCE;

  const int lrow = lane & 15, k8 = lane >> 4;
  bf16x8 bfr[4];

  for (int t = 0; t < NT; ++t) {
    const int slot = t & 3;
    const int sts  = (t + 3) & 3;
    const unsigned short* Asl = As + slot*(256*32);
    const unsigned short* Bsl = Bs + slot*(256*32);

    // ---- phase 0: quadrant mq=0 ----
    bf16x8 af[4];
#pragma unroll
    for (int nj = 0; nj < 4; ++nj) {            // B frags (held both phases)
      const int r = wc*64 + nj*16 + lrow;
      bfr[nj] = *(const bf16x8*)&Bsl[r*32 + (k8 ^ ((r >> 1) & 3))*8];
    }
#pragma unroll
    for (int mi = 0; mi < 4; ++mi) {
      const int r = wr*128 + mi*16 + lrow;
      af[mi] = *(const bf16x8*)&Asl[r*32 + (k8 ^ ((r >> 1) & 3))*8];
    }
    if (t + 3 < NT) STAGE_A(sts, t + 3);
    MEMFENCE;
    __builtin_amdgcn_s_setprio(1);
#pragma unroll
    for (int mi = 0; mi < 4; ++mi)
#pragma unroll
      for (int nj = 0; nj < 4; ++nj)
        acc[mi][nj] = __builtin_amdgcn_mfma_f32_16x16x32_bf16(
                          af[mi], bfr[nj], acc[mi][nj], 0, 0, 0);
    __builtin_amdgcn_s_setprio(0);
    MEMFENCE;

    // ---- phase 1: quadrant mq=1 ----
#pragma unroll
    for (int mi = 0; mi < 4; ++mi) {
      const int r = wr*128 + 64 + mi*16 + lrow;
      af[mi] = *(const bf16x8*)&Asl[r*32 + (k8 ^ ((r >> 1) & 3))*8];
    }
    if (t + 3 < NT) STAGE_B(sts, t + 3);
    MEMFENCE;
    __builtin_amdgcn_s_setprio(1);
#pragma unroll
    for (int mi = 0; mi < 4; ++mi)
#pragma unroll
      for (int nj = 0; nj < 4; ++nj)
        acc[mi + 4][nj] = __builtin_amdgcn_mfma_f32_16x16x32_bf16(
                              af[mi], bfr[nj], acc[mi + 4][nj], 0, 0, 0);
    __builtin_amdgcn_s_setprio(0);

    // ---- tile boundary: wait next tile staged, keep rest in flight ----
    if (t <= NT - 4)      asm volatile("s_waitcnt vmcnt(8)" ::: "memory");
    else if (t == NT - 3) asm volatile("s_waitcnt vmcnt(4)" ::: "memory");
    else                  asm volatile("s_waitcnt vmcnt(0)" ::: "memory");
    __builtin_amdgcn_s_barrier();
    MEMFENCE;
  }

  // epilogue
  const int lcol = lane & 15, lrq = lane >> 4;
#pragma unroll
  for (int nj = 0; nj < 4; ++nj) {
    const int colg = bx*256 + wc*64 + nj*16 + lcol;
    const float bv = bias[colg];
#pragma unroll
    for (int mi = 0; mi < 8; ++mi) {
      const int rowg = by*256 + wr*128 + mi*16 + lrq*4;
#pragma unroll
      for (int q = 0; q < 4; ++q)
        Cout[(size_t)(rowg + q)*4096 + colg] = f2bf(acc[mi][nj][q] + bv);
    }
  }
}

// ---------------------------------------------------------------------------
// bf16 MFMA GEMM (proven 2-phase dbuf).  SPLITK: grid.y = k-slice of width K,
// A/B row stride = 2K, fp32 partial out (no bias).
// ---------------------------------------------------------------------------
template<int BN, int BK, bool OUT_BF16, int LDC, int ACT, bool SPLITK = false>
__global__ __launch_bounds__(256, 4) void gemm2_kernel(
    const unsigned short* __restrict__ A,
    const unsigned short* __restrict__ B,
    const float* __restrict__ bias,
    void* __restrict__ Cout, int K, int nbx)
{
  constexpr int NH = BK / 32;
  constexpr int NJ = BN / 32;
  __shared__ unsigned short Abuf[2][NH][128*32];
  __shared__ unsigned short Bbuf[2][NH][BN*32];

  const int nwg = gridDim.x;
  const int cpx = nwg >> 3;
  const int bid = blockIdx.x;
  const int swz = (bid & 7) * cpx + (bid >> 3);
  const int bx = swz % nbx;
  const int by = swz / nbx;

  const int stride = SPLITK ? 2*K : K;
  const int koff   = SPLITK ? blockIdx.y * K : 0;

  const int tid  = threadIdx.x;
  const int lane = tid & 63;
  const int wid  = tid >> 6;
  const int wr   = wid >> 1;
  const int wc   = wid & 1;
  const int lr    = lane >> 2;
  const int lslot = lane & 3;

  f32x4 zero = {0.f, 0.f, 0.f, 0.f};
  f32x4 acc[4][NJ];
#pragma unroll
  for (int i = 0; i < 4; ++i)
#pragma unroll
    for (int j = 0; j < NJ; ++j) acc[i][j] = zero;

  const size_t arow0 = (size_t)by * 128;
  const size_t brow0 = (size_t)bx * BN;
  const int NT = K / BK;

  auto STAGE = [&](int buf, int k0) {
#pragma unroll
    for (int half = 0; half < NH; ++half) {
#pragma unroll
      for (int i = 0; i < 2; ++i) {
        const int Rb = (wid + i*4) * 16;
        const int r  = Rb + lr;
        const int c8 = lslot ^ ((r >> 1) & 3);
        const unsigned short* ga = A + (arow0 + r)*(size_t)stride + koff + k0 + half*32 + c8*8;
        __builtin_amdgcn_global_load_lds(
            (const __attribute__((address_space(1))) void*)ga,
            (__attribute__((address_space(3))) void*)(&Abuf[buf][half][Rb*32]),
            16, 0, 0);
      }
#pragma unroll
      for (int i = 0; i < BN/64; ++i) {
        const int Rb = (wid + i*4) * 16;
        const int r  = Rb + lr;
        const int c8 = lslot ^ ((r >> 1) & 3);
        const unsigned short* gb = B + (brow0 + r)*(size_t)stride + koff + k0 + half*32 + c8*8;
        __builtin_amdgcn_global_load_lds(
            (const __attribute__((address_space(1))) void*)gb,
            (__attribute__((address_space(3))) void*)(&Bbuf[buf][half][Rb*32]),
            16, 0, 0);
      }
    }
  };

  STAGE(0, 0);
  __syncthreads();

  const int lrow = lane & 15, k8 = lane >> 4;
  int cur = 0;
  for (int kt = 0; kt < NT; ++kt) {
    if (kt + 1 < NT) STAGE(cur ^ 1, (kt + 1) * BK);

#pragma unroll
    for (int half = 0; half < NH; ++half) {
      bf16x8 af[4], bfr[NJ];
#pragma unroll
      for (int mi = 0; mi < 4; ++mi) {
        const int r = wr*64 + mi*16 + lrow;
        af[mi] = *(const bf16x8*)&Abuf[cur][half][r*32 + (k8 ^ ((r >> 1) & 3))*8];
      }
#pragma unroll
      for (int nj = 0; nj < NJ; ++nj) {
        const int r = wc*(BN/2) + nj*16 + lrow;
        bfr[nj] = *(const bf16x8*)&Bbuf[cur][half][r*32 + (k8 ^ ((r >> 1) & 3))*8];
      }
      __builtin_amdgcn_s_setprio(1);
#pragma unroll
      for (int mi = 0; mi < 4; ++mi)
#pragma unroll
        for (int nj = 0; nj < NJ; ++nj)
          acc[mi][nj] = __builtin_amdgcn_mfma_f32_16x16x32_bf16(
                            af[mi], bfr[nj], acc[mi][nj], 0, 0, 0);
      __builtin_amdgcn_s_setprio(0);
    }
    __syncthreads();
    cur ^= 1;
  }

  const int lcol = lane & 15, lrq = lane >> 4;
  float* outp = (float*)Cout;
  if constexpr (SPLITK) outp += (size_t)blockIdx.y * MT * LDC;
#pragma unroll
  for (int nj = 0; nj < NJ; ++nj) {
    const int colg = bx*BN + wc*(BN/2) + nj*16 + lcol;
    const float bv = SPLITK ? 0.f : bias[colg];
#pragma unroll
    for (int mi = 0; mi < 4; ++mi) {
      const int rowg = by*128 + wr*64 + mi*16 + lrq*4;
#pragma unroll
      for (int q = 0; q < 4; ++q) {
        float v = acc[mi][nj][q] + bv;
        if constexpr (ACT == 1) {
          float e = fexp2(-1.44269504f * fabsf(v));
          v = fmaxf(v, 0.f) + 0.69314718f * flog2(1.f + e);
        }
        if constexpr (OUT_BF16)
          ((unsigned short*)Cout)[(size_t)(rowg + q)*LDC + colg] = f2bf(v);
        else
          outp[(size_t)(rowg + q)*LDC + colg] = v;
      }
    }
  }
}

// ---------------------------------------------------------------------------
// out = partial0 + partial1 + bias   (stage-5 split-K reduce)
// ---------------------------------------------------------------------------
__global__ __launch_bounds__(256) void out_reduce_kernel(
    const float* __restrict__ part, const float* __restrict__ bias,
    float* __restrict__ out)
{
  const int gid = blockIdx.x*256 + threadIdx.x;   // over MT*DM/4
  const int c4  = gid & (DM/4 - 1);
  float4 p0 = ((const float4*)part)[gid];
  float4 p1 = ((const float4*)part)[gid + MT*DM/4];
  float4 bv = ((const float4*)bias)[c4];
  float4 o = { p0.x+p1.x+bv.x, p0.y+p1.y+bv.y, p0.z+p1.z+bv.z, p0.w+p1.w+bv.w };
  ((float4*)out)[gid] = o;
}

// ---------------------------------------------------------------------------
// dbc partials: x @ W_x^T, K split 4 ways. grid (MT/64, 4).
// ---------------------------------------------------------------------------
__global__ __launch_bounds__(256) void dbc_mfma_kernel(
    const unsigned short* __restrict__ A,
    const unsigned short* __restrict__ Bw,
    float* __restrict__ partial)
{
  __shared__ unsigned short Abuf[64*32];
  __shared__ unsigned short Bbuf[96*32];

  const int tid  = threadIdx.x;
  const int lane = tid & 63;
  const int wid  = tid >> 6;
  const int lr    = lane >> 2;
  const int lslot = lane & 3;
  const size_t arow0 = (size_t)blockIdx.x * 64;
  const int ks   = blockIdx.y;
  const int k0b  = ks * (DI/4);

  f32x4 zero = {0.f, 0.f, 0.f, 0.f};
  f32x4 acc[6];
#pragma unroll
  for (int j = 0; j < 6; ++j) acc[j] = zero;

  for (int k0 = k0b; k0 < k0b + DI/4; k0 += 32) {
    {
      const int Rb = wid*16;
      const int r  = Rb + lr;
      const int c8 = lslot ^ ((r >> 1) & 3);
      const unsigned short* ga = A + (arow0 + r)*4096 + k0 + c8*8;
      __builtin_amdgcn_global_load_lds(
          (const __attribute__((address_space(1))) void*)ga,
          (__attribute__((address_space(3))) void*)(Abuf + Rb*32), 16, 0, 0);
    }
    if (wid < 3) {
#pragma unroll
      for (int i = 0; i < 2; ++i) {
        const int Rb = wid*32 + i*16;
        const int r  = Rb + lr;
        const int c8 = lslot ^ ((r >> 1) & 3);
        const unsigned short* gb = Bw + (size_t)r*DI + k0 + c8*8;
        __builtin_amdgcn_global_load_lds(
            (const __attribute__((address_space(1))) void*)gb,
            (__attribute__((address_space(3))) void*)(Bbuf + Rb*32), 16, 0, 0);
      }
    }
    __syncthreads();

    const int lrow = lane & 15, k8 = lane >> 4;
    const int ra = wid*16 + lrow;
    bf16x8 af = *(const bf16x8*)&Abuf[ra*32 + (k8 ^ ((ra >> 1) & 3))*8];
#pragma unroll
    for (int nj = 0; nj < 6; ++nj) {
      const int rb = nj*16 + lrow;
      bf16x8 bf_ = *(const bf16x8*)&Bbuf[rb*32 + (k8 ^ ((rb >> 1) & 3))*8];
      acc[nj] = __builtin_amdgcn_mfma_f32_16x16x32_bf16(af, bf_, acc[nj], 0, 0, 0);
    }
    __syncthreads();
  }

  const int lcol = lane & 15, lrq = lane >> 4;
  const int rowg = (int)arow0 + wid*16 + lrq*4;
#pragma unroll
  for (int nj = 0; nj < 6; ++nj) {
    const int colg = nj*16 + lcol;
#pragma unroll
    for (int q = 0; q < 4; ++q)
      partial[((size_t)ks*MT + rowg + q)*96 + colg] = acc[nj][q];
  }
}

// ---------------------------------------------------------------------------
__global__ __launch_bounds__(256) void dbc_reduce_kernel(
    const float* __restrict__ partial, const float* __restrict__ bx,
    float* __restrict__ dbc, unsigned short* __restrict__ draw_bf)
{
  const int gid = blockIdx.x*256 + threadIdx.x;
  const int m = gid / 96;
  const int c = gid - m*96;
  const size_t stride = (size_t)MT*96;
  float s = partial[gid] + partial[gid + stride]
          + partial[gid + 2*stride] + partial[gid + 3*stride] + bx[c];
  if (c < 64) draw_bf[(size_t)m*64 + c] = f2bf(s);
  else        dbc[(size_t)m*96 + c] = s;
}

// ---------------------------------------------------------------------------
// Chunked scan, pass A
// ---------------------------------------------------------------------------
__global__ __launch_bounds__(256) void scanA_kernel(
    const unsigned short* __restrict__ uib,
    const float* __restrict__ dbc,
    const unsigned short* __restrict__ delta_bf,
    const float* __restrict__ A2tab,
    float* __restrict__ P,
    float* __restrict__ S)
{
  const int bid = blockIdx.x;
  const int d   = (bid & 7)*256 + threadIdx.x;
  const int c   = (bid >> 3) & (CHK-1);
  const int b   = bid >> 9;

  float A2[NST];
  {
    const float4* ap = (const float4*)(A2tab + (size_t)d*NST);
#pragma unroll
    for (int q = 0; q < 4; ++q) {
      float4 v = ap[q];
      A2[q*4+0] = v.x; A2[q*4+1] = v.y; A2[q*4+2] = v.z; A2[q*4+3] = v.w;
    }
  }

  float h[NST];
#pragma unroll
  for (int nn = 0; nn < NST; ++nn) h[nn] = 0.f;
  float sdt = 0.f;

  const int t0 = c * LCH;
  const unsigned short* dptr = delta_bf + ((size_t)b*SEQ + t0)*DI + d;
  const unsigned short* xptr = uib      + ((size_t)b*SEQ + t0)*4096 + d;
  const float* bptr          = dbc      + ((size_t)b*SEQ + t0)*96 + 64;

  float dt = bf2f(dptr[0]);
  float xv = bf2f(xptr[0]);
  float4 Bv0 = *(const float4*)(bptr + 0);
  float4 Bv1 = *(const float4*)(bptr + 4);
  float4 Bv2 = *(const float4*)(bptr + 8);
  float4 Bv3 = *(const float4*)(bptr + 12);

  for (int t = 0; t < LCH; ++t) {
    const float dtc = dt, xvc = xv;
    float Bc[NST] = {Bv0.x,Bv0.y,Bv0.z,Bv0.w, Bv1.x,Bv1.y,Bv1.z,Bv1.w,
                     Bv2.x,Bv2.y,Bv2.z,Bv2.w, Bv3.x,Bv3.y,Bv3.z,Bv3.w};
    if (t + 1 < LCH) {
      const size_t tn = (size_t)(t+1);
      dt = bf2f(dptr[tn*DI]);
      xv = bf2f(xptr[tn*4096]);
      const float* bp = bptr + tn*96;
      Bv0 = *(const float4*)(bp + 0);
      Bv1 = *(const float4*)(bp + 4);
      Bv2 = *(const float4*)(bp + 8);
      Bv3 = *(const float4*)(bp + 12);
    }
    sdt += dtc;
    const float xdt = xvc * dtc;
#pragma unroll
    for (int nn = 0; nn < NST; ++nn) {
      float dA = fexp2(dtc * A2[nn]);
      h[nn] = h[nn]*dA + xdt*Bc[nn];
    }
  }

  float* Pp = P + (((size_t)b*CHK + c)*DI + d)*NST;
  float* Sp = S + (((size_t)b*CHK + c)*DI + d)*NST;
#pragma unroll
  for (int q = 0; q < 4; ++q) {
    float4 pv = { fexp2(A2[q*4+0]*sdt), fexp2(A2[q*4+1]*sdt),
                  fexp2(A2[q*4+2]*sdt), fexp2(A2[q*4+3]*sdt) };
    float4 sv = { h[q*4+0], h[q*4+1], h[q*4+2], h[q*4+3] };
    *(float4*)(Pp + q*4) = pv;
    *(float4*)(Sp + q*4) = sv;
  }
}

// ---------------------------------------------------------------------------
__global__ __launch_bounds__(256) void scanB_kernel(
    const float* __restrict__ P, float* __restrict__ S)
{
  const int gid = blockIdx.x*256 + threadIdx.x;
  const int n4 = gid & 3;
  const int d  = (gid >> 2) & (DI-1);
  const int b  = gid >> 13;

  float4 h = {0.f, 0.f, 0.f, 0.f};
  for (int c = 0; c < CHK; ++c) {
    const size_t idx = (((size_t)b*CHK + c)*DI + d)*NST + n4*4;
    float4 p = *(const float4*)(P + idx);
    float4 s = *(const float4*)(S + idx);
    *(float4*)(S + idx) = h;
    h.x = h.x*p.x + s.x;
    h.y = h.y*p.y + s.y;
    h.z = h.z*p.z + s.z;
    h.w = h.w*p.w + s.w;
  }
}

// ---------------------------------------------------------------------------
__global__ __launch_bounds__(256) void scanC_kernel(
    const unsigned short* __restrict__ uib,
    const float* __restrict__ dbc,
    const unsigned short* __restrict__ delta_bf,
    const float* __restrict__ A2tab,
    const float* __restrict__ Dp,
    const float* __restrict__ S,
    unsigned short* __restrict__ y_bf)
{
  const int bid = blockIdx.x;
  const int d   = (bid & 7)*256 + threadIdx.x;
  const int c   = (bid >> 3) & (CHK-1);
  const int b   = bid >> 9;

  float A2[NST];
  {
    const float4* ap = (const float4*)(A2tab + (size_t)d*NST);
#pragma unroll
    for (int q = 0; q < 4; ++q) {
      float4 v = ap[q];
      A2[q*4+0] = v.x; A2[q*4+1] = v.y; A2[q*4+2] = v.z; A2[q*4+3] = v.w;
    }
  }
  const float Dv = Dp[d];

  float h[NST];
  {
    const float* Sp = S + (((size_t)b*CHK + c)*DI + d)*NST;
#pragma unroll
    for (int q = 0; q < 4; ++q) {
      float4 sv = *(const float4*)(Sp + q*4);
      h[q*4+0] = sv.x; h[q*4+1] = sv.y; h[q*4+2] = sv.z; h[q*4+3] = sv.w;
    }
  }

  const int t0 = c * LCH;
  const unsigned short* dptr = delta_bf + ((size_t)b*SEQ + t0)*DI + d;
  const unsigned short* xptr = uib      + ((size_t)b*SEQ + t0)*4096 + d;
  const float* cptr          = dbc      + ((size_t)b*SEQ + t0)*96;
  unsigned short* yp         = y_bf     + ((size_t)b*SEQ + t0)*DI + d;

  float dt = bf2f(dptr[0]);
  float xv = bf2f(xptr[0]);
  float zv = bf2f(xptr[2048]);
  float4 Bv0 = *(const float4*)(cptr + 64);
  float4 Bv1 = *(const float4*)(cptr + 68);
  float4 Bv2 = *(const float4*)(cptr + 72);
  float4 Bv3 = *(const float4*)(cptr + 76);
  float4 Cv0 = *(const float4*)(cptr + 80);
  float4 Cv1 = *(const float4*)(cptr + 84);
  float4 Cv2 = *(const float4*)(cptr + 88);
  float4 Cv3 = *(const float4*)(cptr + 92);

  for (int t = 0; t < LCH; ++t) {
    const float dtc = dt, xvc = xv, zvc = zv;
    float Bc[NST] = {Bv0.x,Bv0.y,Bv0.z,Bv0.w, Bv1.x,Bv1.y,Bv1.z,Bv1.w,
                     Bv2.x,Bv2.y,Bv2.z,Bv2.w, Bv3.x,Bv3.y,Bv3.z,Bv3.w};
    float Cc[NST] = {Cv0.x,Cv0.y,Cv0.z,Cv0.w, Cv1.x,Cv1.y,Cv1.z,Cv1.w,
                     Cv2.x,Cv2.y,Cv2.z,Cv2.w, Cv3.x,Cv3.y,Cv3.z,Cv3.w};
    if (t + 1 < LCH) {
      const size_t tn = (size_t)(t+1);
      dt = bf2f(dptr[tn*DI]);
      xv = bf2f(xptr[tn*4096]);
      zv = bf2f(xptr[tn*4096 + 2048]);
      const float* cp = cptr + tn*96;
      Bv0 = *(const float4*)(cp + 64);
      Bv1 = *(const float4*)(cp + 68);
      Bv2 = *(const float4*)(cp + 72);
      Bv3 = *(const float4*)(cp + 76);
      Cv0 = *(const float4*)(cp + 80);
      Cv1 = *(const float4*)(cp + 84);
      Cv2 = *(const float4*)(cp + 88);
      Cv3 = *(const float4*)(cp + 92);
    }
    const float xdt = xvc * dtc;
    float y = 0.f;
#pragma unroll
    for (int nn = 0; nn < NST; ++nn) {
      float dA = fexp2(dtc * A2[nn]);
      h[nn] = h[nn]*dA + xdt*Bc[nn];
      y += h[nn]*Cc[nn];
    }
    y += xvc * Dv;
    y *= zvc / (1.f + fexp2(-1.44269504f * zvc));
    yp[(size_t)t*DI] = f2bf(y);
  }
}

// ---------------------------------------------------------------------------
extern "C" void kernel_launch(void* const* d_in, const int* in_sizes, int n_in,
                              void* d_out, int out_size, void* d_ws, size_t ws_size,
                              hipStream_t stream)
{
  const float* u     = (const float*)d_in[0];
  const float* W_in  = (const float*)d_in[1];
  const float* b_in  = (const float*)d_in[2];
  const float* W_x   = (const float*)d_in[3];
  const float* b_x   = (const float*)d_in[4];
  const float* W_dt  = (const float*)d_in[5];
  const float* b_dt  = (const float*)d_in[6];
  const float* A_log = (const float*)d_in[7];
  const float* Dp    = (const float*)d_in[8];
  const float* W_out = (const float*)d_in[9];
  const float* b_out = (const float*)d_in[10];
  float* out = (float*)d_out;

  unsigned short* ui_bf    = (unsigned short*)d_ws;
  float*          dbc      = (float*)(ui_bf + (size_t)MT*4096);
  unsigned short* delta_bf = (unsigned short*)(dbc + (size_t)MT*96);
  unsigned short* y_bf     = delta_bf + (size_t)MT*DI;
  unsigned short* wout_bf  = y_bf + (size_t)MT*DI;
  unsigned short* wx_bf    = wout_bf + (size_t)DM*DI;
  unsigned short* wdt_bf   = wx_bf + (size_t)96*DI;
  unsigned short* draw_bf  = wdt_bf + (size_t)DI*64;
  float*          S        = (float*)(draw_bf + (size_t)MT*64);
  float*          A2tab    = S + (size_t)BATCH*CHK*DI*NST;
  float*          partial  = A2tab + (size_t)DI*NST;

  unsigned short* u_bf   = (unsigned short*)d_out;
  unsigned short* win_bf = u_bf + (size_t)MT*DM;
  float* P = (float*)d_out;
  // stage-5 split-K partials overlay ui_bf (dead after scanC): 2*MT*DM f32
  float* pK = (float*)d_ws;

  // 0) conversions + A2 table
  convall_kernel<<<CUM5/256, 256, 0, stream>>>(
      u, W_in, W_out, W_x, W_dt, A_log,
      u_bf, win_bf, wout_bf, wx_bf, wdt_bf, A2tab);

  // 1) ui = u @ W_in^T + b_in  — counted-vmcnt 256^2 pipeline (128 KiB LDS);
  //    fall back to proven 2-phase kernel if the attribute isn't grantable.
  bool big = hipFuncSetAttribute(
      (const void*)gemm3_kernel<DM>,
      hipFuncAttributeMaxDynamicSharedMemorySize, 131072) == hipSuccess;
  if (big) {
    gemm3_kernel<DM><<<16*16, 512, 131072, stream>>>(
        u_bf, win_bf, b_in, ui_bf, 16);
  } else {
    gemm2_kernel<128, 32, true, 4096, 0><<<32*32, 256, 0, stream>>>(
        u_bf, win_bf, b_in, ui_bf, DM, 32);
  }

  // 2) dbc partials (K-split x4) + reduce
  dbc_mfma_kernel<<<dim3(MT/64, 4), 256, 0, stream>>>(ui_bf, wx_bf, partial);
  dbc_reduce_kernel<<<MT*96/256, 256, 0, stream>>>(partial, b_x, dbc, draw_bf);

  // 3) delta = softplus(draw @ W_dt^T + b_dt)
  gemm2_kernel<128, 32, true, 2048, 1><<<16*32, 256, 0, stream>>>(
      draw_bf, wdt_bf, b_dt, delta_bf, 64, 16);

  // 4) chunk-parallel selective scan
  scanA_kernel<<<BATCH*CHK*DI/256, 256, 0, stream>>>(ui_bf, dbc, delta_bf, A2tab, P, S);
  scanB_kernel<<<BATCH*DI*4/256, 256, 0, stream>>>(P, S);
  scanC_kernel<<<BATCH*CHK*DI/256, 256, 0, stream>>>(ui_bf, dbc, delta_bf, A2tab, Dp, S, y_bf);

  // 5) out = y @ W_out^T + b_out — split-K x2 (fp32 partials into pK, which
  //    overlays the now-dead ui_bf), then reduce + bias.
  gemm2_kernel<128, 32, false, 1024, 0, true><<<dim3(8*32, 2), 256, 0, stream>>>(
      y_bf, wout_bf, nullptr, pK, 1024, 8);
  out_reduce_kernel<<<MT*DM/4/256, 256, 0, stream>>>(pK, b_out, out);
}

// Round 12
// 182.778 us; speedup vs baseline: 1.0587x; 1.0587x over previous
//
#include <hip/hip_runtime.h>
#include <math.h>

#define BATCH 2
#define SEQ   2048
#define DM    1024
#define DI    2048
#define NST   16
#define MT    (BATCH*SEQ)   // 4096
#define CHK   64            // chunks along T
#define LCH   (SEQ/CHK)     // 32 steps per chunk

typedef __attribute__((ext_vector_type(8))) short  bf16x8;
typedef __attribute__((ext_vector_type(4))) float  f32x4;

static __device__ __forceinline__ unsigned short f2bf(float f) {
  unsigned u = __float_as_uint(f);
  u += 0x7fff + ((u >> 16) & 1);          // RNE
  return (unsigned short)(u >> 16);
}
static __device__ __forceinline__ float bf2f(unsigned short h) {
  return __uint_as_float(((unsigned)h) << 16);
}
static __device__ __forceinline__ float fexp2(float x) {
  float r;
  asm("v_exp_f32 %0, %1" : "=v"(r) : "v"(x));
  return r;
}
static __device__ __forceinline__ float flog2(float x) {
  float r;
  asm("v_log_f32 %0, %1" : "=v"(r) : "v"(x));
  return r;
}

// ---------------------------------------------------------------------------
// Fused fp32->bf16 conversions + A2 table, one launch.
// ---------------------------------------------------------------------------
#define SEG_U    (MT*DM/4)
#define SEG_WIN  (2*DI*DM/4)
#define SEG_WOUT (DM*DI/4)
#define SEG_WX   (96*DI/4)
#define SEG_WDT  (DI*64/4)
#define SEG_A    (DI*NST/4)
#define CUM0 SEG_U
#define CUM1 (CUM0+SEG_WIN)
#define CUM2 (CUM1+SEG_WOUT)
#define CUM3 (CUM2+SEG_WX)
#define CUM4 (CUM3+SEG_WDT)
#define CUM5 (CUM4+SEG_A)

__global__ __launch_bounds__(256) void convall_kernel(
    const float* __restrict__ u, const float* __restrict__ W_in,
    const float* __restrict__ W_out, const float* __restrict__ W_x,
    const float* __restrict__ W_dt, const float* __restrict__ A_log,
    unsigned short* __restrict__ u_bf, unsigned short* __restrict__ win_bf,
    unsigned short* __restrict__ wout_bf, unsigned short* __restrict__ wx_bf,
    unsigned short* __restrict__ wdt_bf, float* __restrict__ A2tab)
{
  const int gid = blockIdx.x*256 + threadIdx.x;
  const float4* src; ushort4* dst; int idx;
  if (gid < CUM0)      { idx = gid;        src = (const float4*)u;     dst = (ushort4*)u_bf; }
  else if (gid < CUM1) { idx = gid - CUM0; src = (const float4*)W_in;  dst = (ushort4*)win_bf; }
  else if (gid < CUM2) { idx = gid - CUM1; src = (const float4*)W_out; dst = (ushort4*)wout_bf; }
  else if (gid < CUM3) { idx = gid - CUM2; src = (const float4*)W_x;   dst = (ushort4*)wx_bf; }
  else if (gid < CUM4) { idx = gid - CUM3; src = (const float4*)W_dt;  dst = (ushort4*)wdt_bf; }
  else if (gid < CUM5) {
    int i = gid - CUM4;
    float4 v = ((const float4*)A_log)[i];
    float4 o;
    o.x = -1.44269504f * __expf(v.x);
    o.y = -1.44269504f * __expf(v.y);
    o.z = -1.44269504f * __expf(v.z);
    o.w = -1.44269504f * __expf(v.w);
    ((float4*)A2tab)[i] = o;
    return;
  } else return;
  float4 v = src[idx];
  ushort4 o;
  o.x = f2bf(v.x); o.y = f2bf(v.y); o.z = f2bf(v.z); o.w = f2bf(v.w);
  dst[idx] = o;
}

// ---------------------------------------------------------------------------
// gemm3: 256x256 tile, BK=32, ring-4 LDS (128 KiB dynamic), 512 thr = 8 waves
// (2M x 4N).  Counted-vmcnt pipeline, one barrier per tile.
// ---------------------------------------------------------------------------
#define MEMFENCE asm volatile("" ::: "memory")

template<int K>
__global__ __launch_bounds__(512, 2) void gemm3_kernel(
    const unsigned short* __restrict__ A,
    const unsigned short* __restrict__ B,
    const float* __restrict__ bias,
    unsigned short* __restrict__ Cout, int nbx)
{
  extern __shared__ unsigned short smem[];
  unsigned short* As = smem;                 // [4][256*32]
  unsigned short* Bs = smem + 4*256*32;      // [4][256*32]
  constexpr int NT = K / 32;

  const int nwg = gridDim.x;
  const int cpx = nwg >> 3;
  const int bid = blockIdx.x;
  const int swz = (bid & 7) * cpx + (bid >> 3);
  const int bx = swz % nbx;
  const int by = swz / nbx;

  const int tid  = threadIdx.x;
  const int lane = tid & 63;
  const int wid  = tid >> 6;          // 0..7
  const int wr   = wid >> 2;          // 0..1  (M half)
  const int wc   = wid & 3;           // 0..3  (N quarter)

  const size_t arow0 = (size_t)by * 256;
  const size_t brow0 = (size_t)bx * 256;

  const int s_r4 = lane >> 2;         // 0..15
  const int s_c  = lane & 3;          // chunk 0..3

  auto STAGE_A = [&](int slot, int T) {
#pragma unroll
    for (int i = 0; i < 2; ++i) {
      const int r  = wid*32 + i*16 + s_r4;
      const int lc = s_c ^ ((r >> 1) & 3);
      const unsigned short* g = A + (arow0 + r)*(size_t)K + T*32 + lc*8;
      __builtin_amdgcn_global_load_lds(
          (const __attribute__((address_space(1))) void*)g,
          (__attribute__((address_space(3))) void*)(As + slot*(256*32) + (wid*32 + i*16)*32),
          16, 0, 0);
    }
  };
  auto STAGE_B = [&](int slot, int T) {
#pragma unroll
    for (int i = 0; i < 2; ++i) {
      const int r  = wid*32 + i*16 + s_r4;
      const int lc = s_c ^ ((r >> 1) & 3);
      const unsigned short* g = B + (brow0 + r)*(size_t)K + T*32 + lc*8;
      __builtin_amdgcn_global_load_lds(
          (const __attribute__((address_space(1))) void*)g,
          (__attribute__((address_space(3))) void*)(Bs + slot*(256*32) + (wid*32 + i*16)*32),
          16, 0, 0);
    }
  };

  f32x4 zero = {0.f, 0.f, 0.f, 0.f};
  f32x4 acc[8][4];
#pragma unroll
  for (int i = 0; i < 8; ++i)
#pragma unroll
    for (int j = 0; j < 4; ++j) acc[i][j] = zero;

  STAGE_A(0, 0); STAGE_B(0, 0);
  STAGE_A(1, 1); STAGE_B(1, 1);
  STAGE_A(2, 2); STAGE_B(2, 2);
  asm volatile("s_waitcnt vmcnt(8)" ::: "memory");   // tile 0 complete
  __builtin_amdgcn_s_barrier();
  MEMFENCE;

  const int lrow = lane & 15, k8 = lane >> 4;
  bf16x8 bfr[4];

  for (int t = 0; t < NT; ++t) {
    const int slot = t & 3;
    const int sts  = (t + 3) & 3;
    const unsigned short* Asl = As + slot*(256*32);
    const unsigned short* Bsl = Bs + slot*(256*32);

    // ---- phase 0 ----
    bf16x8 af[4];
#pragma unroll
    for (int nj = 0; nj < 4; ++nj) {
      const int r = wc*64 + nj*16 + lrow;
      bfr[nj] = *(const bf16x8*)&Bsl[r*32 + (k8 ^ ((r >> 1) & 3))*8];
    }
#pragma unroll
    for (int mi = 0; mi < 4; ++mi) {
      const int r = wr*128 + mi*16 + lrow;
      af[mi] = *(const bf16x8*)&Asl[r*32 + (k8 ^ ((r >> 1) & 3))*8];
    }
    if (t + 3 < NT) STAGE_A(sts, t + 3);
    MEMFENCE;
    __builtin_amdgcn_s_setprio(1);
#pragma unroll
    for (int mi = 0; mi < 4; ++mi)
#pragma unroll
      for (int nj = 0; nj < 4; ++nj)
        acc[mi][nj] = __builtin_amdgcn_mfma_f32_16x16x32_bf16(
                          af[mi], bfr[nj], acc[mi][nj], 0, 0, 0);
    __builtin_amdgcn_s_setprio(0);
    MEMFENCE;

    // ---- phase 1 ----
#pragma unroll
    for (int mi = 0; mi < 4; ++mi) {
      const int r = wr*128 + 64 + mi*16 + lrow;
      af[mi] = *(const bf16x8*)&Asl[r*32 + (k8 ^ ((r >> 1) & 3))*8];
    }
    if (t + 3 < NT) STAGE_B(sts, t + 3);
    MEMFENCE;
    __builtin_amdgcn_s_setprio(1);
#pragma unroll
    for (int mi = 0; mi < 4; ++mi)
#pragma unroll
      for (int nj = 0; nj < 4; ++nj)
        acc[mi + 4][nj] = __builtin_amdgcn_mfma_f32_16x16x32_bf16(
                              af[mi], bfr[nj], acc[mi + 4][nj], 0, 0, 0);
    __builtin_amdgcn_s_setprio(0);

    if (t <= NT - 4)      asm volatile("s_waitcnt vmcnt(8)" ::: "memory");
    else if (t == NT - 3) asm volatile("s_waitcnt vmcnt(4)" ::: "memory");
    else                  asm volatile("s_waitcnt vmcnt(0)" ::: "memory");
    __builtin_amdgcn_s_barrier();
    MEMFENCE;
  }

  const int lcol = lane & 15, lrq = lane >> 4;
#pragma unroll
  for (int nj = 0; nj < 4; ++nj) {
    const int colg = bx*256 + wc*64 + nj*16 + lcol;
    const float bv = bias[colg];
#pragma unroll
    for (int mi = 0; mi < 8; ++mi) {
      const int rowg = by*256 + wr*128 + mi*16 + lrq*4;
#pragma unroll
      for (int q = 0; q < 4; ++q)
        Cout[(size_t)(rowg + q)*4096 + colg] = f2bf(acc[mi][nj][q] + bv);
    }
  }
}

// ---------------------------------------------------------------------------
// bf16 MFMA GEMM (proven 2-phase dbuf) — delta (stage 3) and gemm5 (stage 5).
// ---------------------------------------------------------------------------
template<int BN, int BK, bool OUT_BF16, int LDC, int ACT>
__global__ __launch_bounds__(256, 4) void gemm2_kernel(
    const unsigned short* __restrict__ A,
    const unsigned short* __restrict__ B,
    const float* __restrict__ bias,
    void* __restrict__ Cout, int K, int nbx)
{
  constexpr int NH = BK / 32;
  constexpr int NJ = BN / 32;
  __shared__ unsigned short Abuf[2][NH][128*32];
  __shared__ unsigned short Bbuf[2][NH][BN*32];

  const int nwg = gridDim.x;
  const int cpx = nwg >> 3;
  const int bid = blockIdx.x;
  const int swz = (bid & 7) * cpx + (bid >> 3);
  const int bx = swz % nbx;
  const int by = swz / nbx;

  const int tid  = threadIdx.x;
  const int lane = tid & 63;
  const int wid  = tid >> 6;
  const int wr   = wid >> 1;
  const int wc   = wid & 1;
  const int lr    = lane >> 2;
  const int lslot = lane & 3;

  f32x4 zero = {0.f, 0.f, 0.f, 0.f};
  f32x4 acc[4][NJ];
#pragma unroll
  for (int i = 0; i < 4; ++i)
#pragma unroll
    for (int j = 0; j < NJ; ++j) acc[i][j] = zero;

  const size_t arow0 = (size_t)by * 128;
  const size_t brow0 = (size_t)bx * BN;
  const int NT = K / BK;

  auto STAGE = [&](int buf, int k0) {
#pragma unroll
    for (int half = 0; half < NH; ++half) {
#pragma unroll
      for (int i = 0; i < 2; ++i) {
        const int Rb = (wid + i*4) * 16;
        const int r  = Rb + lr;
        const int c8 = lslot ^ ((r >> 1) & 3);
        const unsigned short* ga = A + (arow0 + r)*(size_t)K + k0 + half*32 + c8*8;
        __builtin_amdgcn_global_load_lds(
            (const __attribute__((address_space(1))) void*)ga,
            (__attribute__((address_space(3))) void*)(&Abuf[buf][half][Rb*32]),
            16, 0, 0);
      }
#pragma unroll
      for (int i = 0; i < BN/64; ++i) {
        const int Rb = (wid + i*4) * 16;
        const int r  = Rb + lr;
        const int c8 = lslot ^ ((r >> 1) & 3);
        const unsigned short* gb = B + (brow0 + r)*(size_t)K + k0 + half*32 + c8*8;
        __builtin_amdgcn_global_load_lds(
            (const __attribute__((address_space(1))) void*)gb,
            (__attribute__((address_space(3))) void*)(&Bbuf[buf][half][Rb*32]),
            16, 0, 0);
      }
    }
  };

  STAGE(0, 0);
  __syncthreads();

  const int lrow = lane & 15, k8 = lane >> 4;
  int cur = 0;
  for (int kt = 0; kt < NT; ++kt) {
    if (kt + 1 < NT) STAGE(cur ^ 1, (kt + 1) * BK);

#pragma unroll
    for (int half = 0; half < NH; ++half) {
      bf16x8 af[4], bfr[NJ];
#pragma unroll
      for (int mi = 0; mi < 4; ++mi) {
        const int r = wr*64 + mi*16 + lrow;
        af[mi] = *(const bf16x8*)&Abuf[cur][half][r*32 + (k8 ^ ((r >> 1) & 3))*8];
      }
#pragma unroll
      for (int nj = 0; nj < NJ; ++nj) {
        const int r = wc*(BN/2) + nj*16 + lrow;
        bfr[nj] = *(const bf16x8*)&Bbuf[cur][half][r*32 + (k8 ^ ((r >> 1) & 3))*8];
      }
      __builtin_amdgcn_s_setprio(1);
#pragma unroll
      for (int mi = 0; mi < 4; ++mi)
#pragma unroll
        for (int nj = 0; nj < NJ; ++nj)
          acc[mi][nj] = __builtin_amdgcn_mfma_f32_16x16x32_bf16(
                            af[mi], bfr[nj], acc[mi][nj], 0, 0, 0);
      __builtin_amdgcn_s_setprio(0);
    }
    __syncthreads();
    cur ^= 1;
  }

  const int lcol = lane & 15, lrq = lane >> 4;
#pragma unroll
  for (int nj = 0; nj < NJ; ++nj) {
    const int colg = bx*BN + wc*(BN/2) + nj*16 + lcol;
    const float bv = bias[colg];
#pragma unroll
    for (int mi = 0; mi < 4; ++mi) {
      const int rowg = by*128 + wr*64 + mi*16 + lrq*4;
#pragma unroll
      for (int q = 0; q < 4; ++q) {
        float v = acc[mi][nj][q] + bv;
        if constexpr (ACT == 1) {
          float e = fexp2(-1.44269504f * fabsf(v));
          v = fmaxf(v, 0.f) + 0.69314718f * flog2(1.f + e);
        }
        if constexpr (OUT_BF16)
          ((unsigned short*)Cout)[(size_t)(rowg + q)*LDC + colg] = f2bf(v);
        else
          ((float*)Cout)[(size_t)(rowg + q)*LDC + colg] = v;
      }
    }
  }
}

// ---------------------------------------------------------------------------
// dbc partials: x @ W_x^T, K split 4 ways. grid (MT/64, 4).
// ---------------------------------------------------------------------------
__global__ __launch_bounds__(256) void dbc_mfma_kernel(
    const unsigned short* __restrict__ A,
    const unsigned short* __restrict__ Bw,
    float* __restrict__ partial)
{
  __shared__ unsigned short Abuf[64*32];
  __shared__ unsigned short Bbuf[96*32];

  const int tid  = threadIdx.x;
  const int lane = tid & 63;
  const int wid  = tid >> 6;
  const int lr    = lane >> 2;
  const int lslot = lane & 3;
  const size_t arow0 = (size_t)blockIdx.x * 64;
  const int ks   = blockIdx.y;
  const int k0b  = ks * (DI/4);

  f32x4 zero = {0.f, 0.f, 0.f, 0.f};
  f32x4 acc[6];
#pragma unroll
  for (int j = 0; j < 6; ++j) acc[j] = zero;

  for (int k0 = k0b; k0 < k0b + DI/4; k0 += 32) {
    {
      const int Rb = wid*16;
      const int r  = Rb + lr;
      const int c8 = lslot ^ ((r >> 1) & 3);
      const unsigned short* ga = A + (arow0 + r)*4096 + k0 + c8*8;
      __builtin_amdgcn_global_load_lds(
          (const __attribute__((address_space(1))) void*)ga,
          (__attribute__((address_space(3))) void*)(Abuf + Rb*32), 16, 0, 0);
    }
    if (wid < 3) {
#pragma unroll
      for (int i = 0; i < 2; ++i) {
        const int Rb = wid*32 + i*16;
        const int r  = Rb + lr;
        const int c8 = lslot ^ ((r >> 1) & 3);
        const unsigned short* gb = Bw + (size_t)r*DI + k0 + c8*8;
        __builtin_amdgcn_global_load_lds(
            (const __attribute__((address_space(1))) void*)gb,
            (__attribute__((address_space(3))) void*)(Bbuf + Rb*32), 16, 0, 0);
      }
    }
    __syncthreads();

    const int lrow = lane & 15, k8 = lane >> 4;
    const int ra = wid*16 + lrow;
    bf16x8 af = *(const bf16x8*)&Abuf[ra*32 + (k8 ^ ((ra >> 1) & 3))*8];
#pragma unroll
    for (int nj = 0; nj < 6; ++nj) {
      const int rb = nj*16 + lrow;
      bf16x8 bf_ = *(const bf16x8*)&Bbuf[rb*32 + (k8 ^ ((rb >> 1) & 3))*8];
      acc[nj] = __builtin_amdgcn_mfma_f32_16x16x32_bf16(af, bf_, acc[nj], 0, 0, 0);
    }
    __syncthreads();
  }

  const int lcol = lane & 15, lrq = lane >> 4;
  const int rowg = (int)arow0 + wid*16 + lrq*4;
#pragma unroll
  for (int nj = 0; nj < 6; ++nj) {
    const int colg = nj*16 + lcol;
#pragma unroll
    for (int q = 0; q < 4; ++q)
      partial[((size_t)ks*MT + rowg + q)*96 + colg] = acc[nj][q];
  }
}

// ---------------------------------------------------------------------------
__global__ __launch_bounds__(256) void dbc_reduce_kernel(
    const float* __restrict__ partial, const float* __restrict__ bx,
    float* __restrict__ dbc, unsigned short* __restrict__ draw_bf)
{
  const int gid = blockIdx.x*256 + threadIdx.x;
  const int m = gid / 96;
  const int c = gid - m*96;
  const size_t stride = (size_t)MT*96;
  float s = partial[gid] + partial[gid + stride]
          + partial[gid + 2*stride] + partial[gid + 3*stride] + bx[c];
  if (c < 64) draw_bf[(size_t)m*64 + c] = f2bf(s);
  else        dbc[(size_t)m*96 + c] = s;
}

// ---------------------------------------------------------------------------
// Chunked scan, pass A.  B rows for the whole chunk staged in LDS (block-
// uniform) — removes 4 VMEM loads/step from the dependent chain.
// ---------------------------------------------------------------------------
__global__ __launch_bounds__(256) void scanA_kernel(
    const unsigned short* __restrict__ uib,
    const float* __restrict__ dbc,
    const unsigned short* __restrict__ delta_bf,
    const float* __restrict__ A2tab,
    float* __restrict__ P,
    float* __restrict__ S)
{
  __shared__ float Bsh[LCH][16];   // 2 KiB
  const int bid = blockIdx.x;
  const int d   = (bid & 7)*256 + threadIdx.x;
  const int c   = (bid >> 3) & (CHK-1);
  const int b   = bid >> 9;
  const int t0  = c * LCH;

  {
    int i = threadIdx.x;
    if (i < LCH*4) {
      int st = i >> 2, p = i & 3;
      float4 v = *(const float4*)(dbc + ((size_t)b*SEQ + t0 + st)*96 + 64 + p*4);
      *(float4*)&Bsh[st][p*4] = v;
    }
  }

  float A2[NST];
  {
    const float4* ap = (const float4*)(A2tab + (size_t)d*NST);
#pragma unroll
    for (int q = 0; q < 4; ++q) {
      float4 v = ap[q];
      A2[q*4+0] = v.x; A2[q*4+1] = v.y; A2[q*4+2] = v.z; A2[q*4+3] = v.w;
    }
  }

  float h[NST];
#pragma unroll
  for (int nn = 0; nn < NST; ++nn) h[nn] = 0.f;
  float sdt = 0.f;

  const unsigned short* dptr = delta_bf + ((size_t)b*SEQ + t0)*DI + d;
  const unsigned short* xptr = uib      + ((size_t)b*SEQ + t0)*4096 + d;

  float dt = bf2f(dptr[0]);
  float xv = bf2f(xptr[0]);
  __syncthreads();

  for (int t = 0; t < LCH; ++t) {
    const float dtc = dt, xvc = xv;
    if (t + 1 < LCH) {
      const size_t tn = (size_t)(t+1);
      dt = bf2f(dptr[tn*DI]);
      xv = bf2f(xptr[tn*4096]);
    }
    float4 Bv0 = *(const float4*)&Bsh[t][0];
    float4 Bv1 = *(const float4*)&Bsh[t][4];
    float4 Bv2 = *(const float4*)&Bsh[t][8];
    float4 Bv3 = *(const float4*)&Bsh[t][12];
    float Bc[NST] = {Bv0.x,Bv0.y,Bv0.z,Bv0.w, Bv1.x,Bv1.y,Bv1.z,Bv1.w,
                     Bv2.x,Bv2.y,Bv2.z,Bv2.w, Bv3.x,Bv3.y,Bv3.z,Bv3.w};
    sdt += dtc;
    const float xdt = xvc * dtc;
#pragma unroll
    for (int nn = 0; nn < NST; ++nn) {
      float dA = fexp2(dtc * A2[nn]);
      h[nn] = h[nn]*dA + xdt*Bc[nn];
    }
  }

  float* Pp = P + (((size_t)b*CHK + c)*DI + d)*NST;
  float* Sp = S + (((size_t)b*CHK + c)*DI + d)*NST;
#pragma unroll
  for (int q = 0; q < 4; ++q) {
    float4 pv = { fexp2(A2[q*4+0]*sdt), fexp2(A2[q*4+1]*sdt),
                  fexp2(A2[q*4+2]*sdt), fexp2(A2[q*4+3]*sdt) };
    float4 sv = { h[q*4+0], h[q*4+1], h[q*4+2], h[q*4+3] };
    *(float4*)(Pp + q*4) = pv;
    *(float4*)(Sp + q*4) = sv;
  }
}

// ---------------------------------------------------------------------------
__global__ __launch_bounds__(256) void scanB_kernel(
    const float* __restrict__ P, float* __restrict__ S)
{
  const int gid = blockIdx.x*256 + threadIdx.x;
  const int n4 = gid & 3;
  const int d  = (gid >> 2) & (DI-1);
  const int b  = gid >> 13;

  float4 h = {0.f, 0.f, 0.f, 0.f};
  for (int c = 0; c < CHK; ++c) {
    const size_t idx = (((size_t)b*CHK + c)*DI + d)*NST + n4*4;
    float4 p = *(const float4*)(P + idx);
    float4 s = *(const float4*)(S + idx);
    *(float4*)(S + idx) = h;
    h.x = h.x*p.x + s.x;
    h.y = h.y*p.y + s.y;
    h.z = h.z*p.z + s.z;
    h.w = h.w*p.w + s.w;
  }
}

// ---------------------------------------------------------------------------
// Chunked scan, pass C.  B+C rows staged in LDS (4 KiB).
// ---------------------------------------------------------------------------
__global__ __launch_bounds__(256) void scanC_kernel(
    const unsigned short* __restrict__ uib,
    const float* __restrict__ dbc,
    const unsigned short* __restrict__ delta_bf,
    const float* __restrict__ A2tab,
    const float* __restrict__ Dp,
    const float* __restrict__ S,
    unsigned short* __restrict__ y_bf)
{
  __shared__ float BCs[LCH][32];   // 4 KiB: [t][0..15]=B, [t][16..31]=C
  const int bid = blockIdx.x;
  const int d   = (bid & 7)*256 + threadIdx.x;
  const int c   = (bid >> 3) & (CHK-1);
  const int b   = bid >> 9;
  const int t0  = c * LCH;

  {
    int i = threadIdx.x;          // 256 threads, LCH*8 = 256 float4 loads
    int st = i >> 3, p = i & 7;
    float4 v = *(const float4*)(dbc + ((size_t)b*SEQ + t0 + st)*96 + 64 + p*4);
    *(float4*)&BCs[st][p*4] = v;
  }

  float A2[NST];
  {
    const float4* ap = (const float4*)(A2tab + (size_t)d*NST);
#pragma unroll
    for (int q = 0; q < 4; ++q) {
      float4 v = ap[q];
      A2[q*4+0] = v.x; A2[q*4+1] = v.y; A2[q*4+2] = v.z; A2[q*4+3] = v.w;
    }
  }
  const float Dv = Dp[d];

  float h[NST];
  {
    const float* Sp = S + (((size_t)b*CHK + c)*DI + d)*NST;
#pragma unroll
    for (int q = 0; q < 4; ++q) {
      float4 sv = *(const float4*)(Sp + q*4);
      h[q*4+0] = sv.x; h[q*4+1] = sv.y; h[q*4+2] = sv.z; h[q*4+3] = sv.w;
    }
  }

  const unsigned short* dptr = delta_bf + ((size_t)b*SEQ + t0)*DI + d;
  const unsigned short* xptr = uib      + ((size_t)b*SEQ + t0)*4096 + d;
  unsigned short* yp         = y_bf     + ((size_t)b*SEQ + t0)*DI + d;

  float dt = bf2f(dptr[0]);
  float xv = bf2f(xptr[0]);
  float zv = bf2f(xptr[2048]);
  __syncthreads();

  for (int t = 0; t < LCH; ++t) {
    const float dtc = dt, xvc = xv, zvc = zv;
    if (t + 1 < LCH) {
      const size_t tn = (size_t)(t+1);
      dt = bf2f(dptr[tn*DI]);
      xv = bf2f(xptr[tn*4096]);
      zv = bf2f(xptr[tn*4096 + 2048]);
    }
    float4 Bv0 = *(const float4*)&BCs[t][0];
    float4 Bv1 = *(const float4*)&BCs[t][4];
    float4 Bv2 = *(const float4*)&BCs[t][8];
    float4 Bv3 = *(const float4*)&BCs[t][12];
    float4 Cv0 = *(const float4*)&BCs[t][16];
    float4 Cv1 = *(const float4*)&BCs[t][20];
    float4 Cv2 = *(const float4*)&BCs[t][24];
    float4 Cv3 = *(const float4*)&BCs[t][28];
    float Bc[NST] = {Bv0.x,Bv0.y,Bv0.z,Bv0.w, Bv1.x,Bv1.y,Bv1.z,Bv1.w,
                     Bv2.x,Bv2.y,Bv2.z,Bv2.w, Bv3.x,Bv3.y,Bv3.z,Bv3.w};
    float Cc[NST] = {Cv0.x,Cv0.y,Cv0.z,Cv0.w, Cv1.x,Cv1.y,Cv1.z,Cv1.w,
                     Cv2.x,Cv2.y,Cv2.z,Cv2.w, Cv3.x,Cv3.y,Cv3.z,Cv3.w};
    const float xdt = xvc * dtc;
    float y = 0.f;
#pragma unroll
    for (int nn = 0; nn < NST; ++nn) {
      float dA = fexp2(dtc * A2[nn]);
      h[nn] = h[nn]*dA + xdt*Bc[nn];
      y += h[nn]*Cc[nn];
    }
    y += xvc * Dv;
    y *= zvc / (1.f + fexp2(-1.44269504f * zvc));
    yp[(size_t)t*DI] = f2bf(y);
  }
}

// ---------------------------------------------------------------------------
extern "C" void kernel_launch(void* const* d_in, const int* in_sizes, int n_in,
                              void* d_out, int out_size, void* d_ws, size_t ws_size,
                              hipStream_t stream)
{
  const float* u     = (const float*)d_in[0];
  const float* W_in  = (const float*)d_in[1];
  const float* b_in  = (const float*)d_in[2];
  const float* W_x   = (const float*)d_in[3];
  const float* b_x   = (const float*)d_in[4];
  const float* W_dt  = (const float*)d_in[5];
  const float* b_dt  = (const float*)d_in[6];
  const float* A_log = (const float*)d_in[7];
  const float* Dp    = (const float*)d_in[8];
  const float* W_out = (const float*)d_in[9];
  const float* b_out = (const float*)d_in[10];
  float* out = (float*)d_out;

  unsigned short* ui_bf    = (unsigned short*)d_ws;
  float*          dbc      = (float*)(ui_bf + (size_t)MT*4096);
  unsigned short* delta_bf = (unsigned short*)(dbc + (size_t)MT*96);
  unsigned short* y_bf     = delta_bf + (size_t)MT*DI;
  unsigned short* wout_bf  = y_bf + (size_t)MT*DI;
  unsigned short* wx_bf    = wout_bf + (size_t)DM*DI;
  unsigned short* wdt_bf   = wx_bf + (size_t)96*DI;
  unsigned short* draw_bf  = wdt_bf + (size_t)DI*64;
  float*          S        = (float*)(draw_bf + (size_t)MT*64);
  float*          A2tab    = S + (size_t)BATCH*CHK*DI*NST;
  float*          partial  = A2tab + (size_t)DI*NST;

  unsigned short* u_bf   = (unsigned short*)d_out;
  unsigned short* win_bf = u_bf + (size_t)MT*DM;
  float* P = (float*)d_out;

  // 0) conversions + A2 table
  convall_kernel<<<CUM5/256, 256, 0, stream>>>(
      u, W_in, W_out, W_x, W_dt, A_log,
      u_bf, win_bf, wout_bf, wx_bf, wdt_bf, A2tab);

  // 1) ui = u @ W_in^T + b_in  — counted-vmcnt 256^2 pipeline (128 KiB LDS);
  //    fall back to proven 2-phase kernel if the attribute isn't grantable.
  bool big = hipFuncSetAttribute(
      (const void*)gemm3_kernel<DM>,
      hipFuncAttributeMaxDynamicSharedMemorySize, 131072) == hipSuccess;
  if (big) {
    gemm3_kernel<DM><<<16*16, 512, 131072, stream>>>(
        u_bf, win_bf, b_in, ui_bf, 16);
  } else {
    gemm2_kernel<128, 32, true, 4096, 0><<<32*32, 256, 0, stream>>>(
        u_bf, win_bf, b_in, ui_bf, DM, 32);
  }

  // 2) dbc partials (K-split x4) + reduce
  dbc_mfma_kernel<<<dim3(MT/64, 4), 256, 0, stream>>>(ui_bf, wx_bf, partial);
  dbc_reduce_kernel<<<MT*96/256, 256, 0, stream>>>(partial, b_x, dbc, draw_bf);

  // 3) delta = softplus(draw @ W_dt^T + b_dt)
  gemm2_kernel<128, 32, true, 2048, 1><<<16*32, 256, 0, stream>>>(
      draw_bf, wdt_bf, b_dt, delta_bf, 64, 16);

  // 4) chunk-parallel selective scan (LDS-staged B/C panels)
  scanA_kernel<<<BATCH*CHK*DI/256, 256, 0, stream>>>(ui_bf, dbc, delta_bf, A2tab, P, S);
  scanB_kernel<<<BATCH*DI*4/256, 256, 0, stream>>>(P, S);
  scanC_kernel<<<BATCH*CHK*DI/256, 256, 0, stream>>>(ui_bf, dbc, delta_bf, A2tab, Dp, S, y_bf);

  // 5) out = y @ W_out^T + b_out — direct (round-8 proven config)
  gemm2_kernel<64, 64, false, 1024, 0><<<16*32, 256, 0, stream>>>(
      y_bf, wout_bf, b_out, out, DI, 16);
}

// Round 13
// 181.897 us; speedup vs baseline: 1.0639x; 1.0048x over previous
//
#include <hip/hip_runtime.h>
#include <math.h>

#define BATCH 2
#define SEQ   2048
#define DM    1024
#define DI    2048
#define NST   16
#define MT    (BATCH*SEQ)   // 4096
#define CHK   64            // chunks along T
#define LCH   (SEQ/CHK)     // 32 steps per chunk

typedef __attribute__((ext_vector_type(8))) short  bf16x8;
typedef __attribute__((ext_vector_type(4))) float  f32x4;

static __device__ __forceinline__ unsigned short f2bf(float f) {
  unsigned u = __float_as_uint(f);
  u += 0x7fff + ((u >> 16) & 1);          // RNE
  return (unsigned short)(u >> 16);
}
static __device__ __forceinline__ float bf2f(unsigned short h) {
  return __uint_as_float(((unsigned)h) << 16);
}
static __device__ __forceinline__ float fexp2(float x) {
  float r;
  asm("v_exp_f32 %0, %1" : "=v"(r) : "v"(x));
  return r;
}
static __device__ __forceinline__ float flog2(float x) {
  float r;
  asm("v_log_f32 %0, %1" : "=v"(r) : "v"(x));
  return r;
}

// ---------------------------------------------------------------------------
// Fused fp32->bf16 conversions + A2 table, one launch.
// ---------------------------------------------------------------------------
#define SEG_U    (MT*DM/4)
#define SEG_WIN  (2*DI*DM/4)
#define SEG_WOUT (DM*DI/4)
#define SEG_WX   (96*DI/4)
#define SEG_WDT  (DI*64/4)
#define SEG_A    (DI*NST/4)
#define CUM0 SEG_U
#define CUM1 (CUM0+SEG_WIN)
#define CUM2 (CUM1+SEG_WOUT)
#define CUM3 (CUM2+SEG_WX)
#define CUM4 (CUM3+SEG_WDT)
#define CUM5 (CUM4+SEG_A)

__global__ __launch_bounds__(256) void convall_kernel(
    const float* __restrict__ u, const float* __restrict__ W_in,
    const float* __restrict__ W_out, const float* __restrict__ W_x,
    const float* __restrict__ W_dt, const float* __restrict__ A_log,
    unsigned short* __restrict__ u_bf, unsigned short* __restrict__ win_bf,
    unsigned short* __restrict__ wout_bf, unsigned short* __restrict__ wx_bf,
    unsigned short* __restrict__ wdt_bf, float* __restrict__ A2tab)
{
  const int gid = blockIdx.x*256 + threadIdx.x;
  const float4* src; ushort4* dst; int idx;
  if (gid < CUM0)      { idx = gid;        src = (const float4*)u;     dst = (ushort4*)u_bf; }
  else if (gid < CUM1) { idx = gid - CUM0; src = (const float4*)W_in;  dst = (ushort4*)win_bf; }
  else if (gid < CUM2) { idx = gid - CUM1; src = (const float4*)W_out; dst = (ushort4*)wout_bf; }
  else if (gid < CUM3) { idx = gid - CUM2; src = (const float4*)W_x;   dst = (ushort4*)wx_bf; }
  else if (gid < CUM4) { idx = gid - CUM3; src = (const float4*)W_dt;  dst = (ushort4*)wdt_bf; }
  else if (gid < CUM5) {
    int i = gid - CUM4;
    float4 v = ((const float4*)A_log)[i];
    float4 o;
    o.x = -1.44269504f * __expf(v.x);
    o.y = -1.44269504f * __expf(v.y);
    o.z = -1.44269504f * __expf(v.z);
    o.w = -1.44269504f * __expf(v.w);
    ((float4*)A2tab)[i] = o;
    return;
  } else return;
  float4 v = src[idx];
  ushort4 o;
  o.x = f2bf(v.x); o.y = f2bf(v.y); o.z = f2bf(v.z); o.w = f2bf(v.w);
  dst[idx] = o;
}

// ---------------------------------------------------------------------------
// gemm3 v2 (m201-style consume-one-phase-later): 256x256 tile, BK=32, ring-4
// LDS (128 KiB dynamic), 512 thr = 8 waves (2M x 4N), wave tile 128x64.
// Each phase: {issue NEXT operands' ds_reads + 1 stage} -> barrier -> MFMA on
// operands read LAST phase -> barrier.  Counted vmcnt(6) at the P1 read head
// guards next-tile slot readiness; never 0 until the tail.  Trailing barrier
// per phase is the WAR guard for staging (all waves' reads drained before any
// wave issues the next stage).
// ---------------------------------------------------------------------------
template<int K>
__global__ __launch_bounds__(512, 2) void gemm3_kernel(
    const unsigned short* __restrict__ A,
    const unsigned short* __restrict__ B,
    const float* __restrict__ bias,
    unsigned short* __restrict__ Cout, int nbx)
{
  extern __shared__ unsigned short smem[];
  unsigned short* As = smem;                 // [4][256*32]
  unsigned short* Bs = smem + 4*256*32;      // [4][256*32]
  constexpr int NT = K / 32;

  const int nwg = gridDim.x;
  const int cpx = nwg >> 3;
  const int bid = blockIdx.x;
  const int swz = (bid & 7) * cpx + (bid >> 3);
  const int bx = swz % nbx;
  const int by = swz / nbx;

  const int tid  = threadIdx.x;
  const int lane = tid & 63;
  const int wid  = tid >> 6;          // 0..7
  const int wr   = wid >> 2;          // 0..1  (M half)
  const int wc   = wid & 3;           // 0..3  (N quarter)

  const size_t arow0 = (size_t)by * 256;
  const size_t brow0 = (size_t)bx * 256;

  const int s_r4 = lane >> 2;         // 0..15
  const int s_c  = lane & 3;          // chunk 0..3

  auto STAGE_A = [&](int slot, int T) {
#pragma unroll
    for (int i = 0; i < 2; ++i) {
      const int r  = wid*32 + i*16 + s_r4;
      const int lc = s_c ^ ((r >> 1) & 3);
      const unsigned short* g = A + (arow0 + r)*(size_t)K + T*32 + lc*8;
      __builtin_amdgcn_global_load_lds(
          (const __attribute__((address_space(1))) void*)g,
          (__attribute__((address_space(3))) void*)(As + slot*(256*32) + (wid*32 + i*16)*32),
          16, 0, 0);
    }
  };
  auto STAGE_B = [&](int slot, int T) {
#pragma unroll
    for (int i = 0; i < 2; ++i) {
      const int r  = wid*32 + i*16 + s_r4;
      const int lc = s_c ^ ((r >> 1) & 3);
      const unsigned short* g = B + (brow0 + r)*(size_t)K + T*32 + lc*8;
      __builtin_amdgcn_global_load_lds(
          (const __attribute__((address_space(1))) void*)g,
          (__attribute__((address_space(3))) void*)(Bs + slot*(256*32) + (wid*32 + i*16)*32),
          16, 0, 0);
    }
  };

  f32x4 zero = {0.f, 0.f, 0.f, 0.f};
  f32x4 acc[8][4];
#pragma unroll
  for (int i = 0; i < 8; ++i)
#pragma unroll
    for (int j = 0; j < 4; ++j) acc[i][j] = zero;

  // prologue: stage tiles 0,1,2 -> 12 loads/thread
  STAGE_A(0, 0); STAGE_B(0, 0);
  STAGE_A(1, 1); STAGE_B(1, 1);
  STAGE_A(2, 2); STAGE_B(2, 2);
  asm volatile("s_waitcnt vmcnt(8)" ::: "memory");   // tile 0 complete
  __builtin_amdgcn_s_barrier();

  const int lrow = lane & 15, k8 = lane >> 4;

  // register ping-pong sets
  bf16x8 af0A[4], af0B[4], bfrA[4], bfrB[4], af1[4];

  // pre-loop: read tile 0's bfr + af_half0 into the A-set
#pragma unroll
  for (int nj = 0; nj < 4; ++nj) {
    const int r = wc*64 + nj*16 + lrow;
    bfrA[nj] = *(const bf16x8*)&Bs[r*32 + (k8 ^ ((r >> 1) & 3))*8];
  }
#pragma unroll
  for (int mi = 0; mi < 4; ++mi) {
    const int r = wr*128 + mi*16 + lrow;
    af0A[mi] = *(const bf16x8*)&As[r*32 + (k8 ^ ((r >> 1) & 3))*8];
  }

#define TILE_BODY(T, AF0C, BFRC, AF0N, BFRN)                                   \
  {                                                                            \
    const int slot_ = (T) & 3;                                                 \
    const unsigned short* Asl_ = As + slot_*(256*32);                          \
    /* P0: issue af_half1 reads + STAGE_A, barrier, MFMA half0, barrier */     \
    _Pragma("unroll")                                                          \
    for (int mi = 0; mi < 4; ++mi) {                                           \
      const int r = wr*128 + 64 + mi*16 + lrow;                                \
      af1[mi] = *(const bf16x8*)&Asl_[r*32 + (k8 ^ ((r >> 1) & 3))*8];         \
    }                                                                          \
    if ((T) + 3 < NT) STAGE_A(((T)+3)&3, (T)+3);                               \
    __builtin_amdgcn_s_barrier();                                              \
    __builtin_amdgcn_s_setprio(1);                                             \
    _Pragma("unroll")                                                          \
    for (int mi = 0; mi < 4; ++mi)                                             \
      _Pragma("unroll")                                                        \
      for (int nj = 0; nj < 4; ++nj)                                           \
        acc[mi][nj] = __builtin_amdgcn_mfma_f32_16x16x32_bf16(                 \
                          AF0C[mi], BFRC[nj], acc[mi][nj], 0, 0, 0);           \
    __builtin_amdgcn_s_setprio(0);                                             \
    __builtin_amdgcn_s_barrier();                                              \
    /* P1: vmcnt gate, issue next tile's bfr+af_half0 + STAGE_B, barrier,  */  \
    /*     MFMA half1, barrier                                              */ \
    if ((T) + 1 < NT) {                                                        \
      if ((T) <= NT - 4)      asm volatile("s_waitcnt vmcnt(6)" ::: "memory"); \
      else if ((T) == NT - 3) asm volatile("s_waitcnt vmcnt(4)" ::: "memory"); \
      else                    asm volatile("s_waitcnt vmcnt(0)" ::: "memory"); \
      const int ns_ = ((T)+1) & 3;                                             \
      const unsigned short* Asn_ = As + ns_*(256*32);                          \
      const unsigned short* Bsn_ = Bs + ns_*(256*32);                          \
      _Pragma("unroll")                                                        \
      for (int nj = 0; nj < 4; ++nj) {                                         \
        const int r = wc*64 + nj*16 + lrow;                                    \
        BFRN[nj] = *(const bf16x8*)&Bsn_[r*32 + (k8 ^ ((r >> 1) & 3))*8];      \
      }                                                                        \
      _Pragma("unroll")                                                        \
      for (int mi = 0; mi < 4; ++mi) {                                         \
        const int r = wr*128 + mi*16 + lrow;                                   \
        AF0N[mi] = *(const bf16x8*)&Asn_[r*32 + (k8 ^ ((r >> 1) & 3))*8];      \
      }                                                                        \
    }                                                                          \
    if ((T) + 3 < NT) STAGE_B(((T)+3)&3, (T)+3);                               \
    __builtin_amdgcn_s_barrier();                                              \
    __builtin_amdgcn_s_setprio(1);                                             \
    _Pragma("unroll")                                                          \
    for (int mi = 0; mi < 4; ++mi)                                             \
      _Pragma("unroll")                                                        \
      for (int nj = 0; nj < 4; ++nj)                                           \
        acc[mi+4][nj] = __builtin_amdgcn_mfma_f32_16x16x32_bf16(               \
                          af1[mi], BFRC[nj], acc[mi+4][nj], 0, 0, 0);          \
    __builtin_amdgcn_s_setprio(0);                                             \
    __builtin_amdgcn_s_barrier();                                              \
  }

  for (int t = 0; t < NT; t += 2) {
    TILE_BODY(t,     af0A, bfrA, af0B, bfrB);
    TILE_BODY(t + 1, af0B, bfrB, af0A, bfrA);
  }
#undef TILE_BODY

  // epilogue
  const int lcol = lane & 15, lrq = lane >> 4;
#pragma unroll
  for (int nj = 0; nj < 4; ++nj) {
    const int colg = bx*256 + wc*64 + nj*16 + lcol;
    const float bv = bias[colg];
#pragma unroll
    for (int mi = 0; mi < 8; ++mi) {
      const int rowg = by*256 + wr*128 + mi*16 + lrq*4;
#pragma unroll
      for (int q = 0; q < 4; ++q)
        Cout[(size_t)(rowg + q)*4096 + colg] = f2bf(acc[mi][nj][q] + bv);
    }
  }
}

// ---------------------------------------------------------------------------
// bf16 MFMA GEMM (proven 2-phase dbuf) — delta (stage 3) and gemm5 (stage 5).
// ---------------------------------------------------------------------------
template<int BN, int BK, bool OUT_BF16, int LDC, int ACT>
__global__ __launch_bounds__(256, 4) void gemm2_kernel(
    const unsigned short* __restrict__ A,
    const unsigned short* __restrict__ B,
    const float* __restrict__ bias,
    void* __restrict__ Cout, int K, int nbx)
{
  constexpr int NH = BK / 32;
  constexpr int NJ = BN / 32;
  __shared__ unsigned short Abuf[2][NH][128*32];
  __shared__ unsigned short Bbuf[2][NH][BN*32];

  const int nwg = gridDim.x;
  const int cpx = nwg >> 3;
  const int bid = blockIdx.x;
  const int swz = (bid & 7) * cpx + (bid >> 3);
  const int bx = swz % nbx;
  const int by = swz / nbx;

  const int tid  = threadIdx.x;
  const int lane = tid & 63;
  const int wid  = tid >> 6;
  const int wr   = wid >> 1;
  const int wc   = wid & 1;
  const int lr    = lane >> 2;
  const int lslot = lane & 3;

  f32x4 zero = {0.f, 0.f, 0.f, 0.f};
  f32x4 acc[4][NJ];
#pragma unroll
  for (int i = 0; i < 4; ++i)
#pragma unroll
    for (int j = 0; j < NJ; ++j) acc[i][j] = zero;

  const size_t arow0 = (size_t)by * 128;
  const size_t brow0 = (size_t)bx * BN;
  const int NT = K / BK;

  auto STAGE = [&](int buf, int k0) {
#pragma unroll
    for (int half = 0; half < NH; ++half) {
#pragma unroll
      for (int i = 0; i < 2; ++i) {
        const int Rb = (wid + i*4) * 16;
        const int r  = Rb + lr;
        const int c8 = lslot ^ ((r >> 1) & 3);
        const unsigned short* ga = A + (arow0 + r)*(size_t)K + k0 + half*32 + c8*8;
        __builtin_amdgcn_global_load_lds(
            (const __attribute__((address_space(1))) void*)ga,
            (__attribute__((address_space(3))) void*)(&Abuf[buf][half][Rb*32]),
            16, 0, 0);
      }
#pragma unroll
      for (int i = 0; i < BN/64; ++i) {
        const int Rb = (wid + i*4) * 16;
        const int r  = Rb + lr;
        const int c8 = lslot ^ ((r >> 1) & 3);
        const unsigned short* gb = B + (brow0 + r)*(size_t)K + k0 + half*32 + c8*8;
        __builtin_amdgcn_global_load_lds(
            (const __attribute__((address_space(1))) void*)gb,
            (__attribute__((address_space(3))) void*)(&Bbuf[buf][half][Rb*32]),
            16, 0, 0);
      }
    }
  };

  STAGE(0, 0);
  __syncthreads();

  const int lrow = lane & 15, k8 = lane >> 4;
  int cur = 0;
  for (int kt = 0; kt < NT; ++kt) {
    if (kt + 1 < NT) STAGE(cur ^ 1, (kt + 1) * BK);

#pragma unroll
    for (int half = 0; half < NH; ++half) {
      bf16x8 af[4], bfr[NJ];
#pragma unroll
      for (int mi = 0; mi < 4; ++mi) {
        const int r = wr*64 + mi*16 + lrow;
        af[mi] = *(const bf16x8*)&Abuf[cur][half][r*32 + (k8 ^ ((r >> 1) & 3))*8];
      }
#pragma unroll
      for (int nj = 0; nj < NJ; ++nj) {
        const int r = wc*(BN/2) + nj*16 + lrow;
        bfr[nj] = *(const bf16x8*)&Bbuf[cur][half][r*32 + (k8 ^ ((r >> 1) & 3))*8];
      }
      __builtin_amdgcn_s_setprio(1);
#pragma unroll
      for (int mi = 0; mi < 4; ++mi)
#pragma unroll
        for (int nj = 0; nj < NJ; ++nj)
          acc[mi][nj] = __builtin_amdgcn_mfma_f32_16x16x32_bf16(
                            af[mi], bfr[nj], acc[mi][nj], 0, 0, 0);
      __builtin_amdgcn_s_setprio(0);
    }
    __syncthreads();
    cur ^= 1;
  }

  const int lcol = lane & 15, lrq = lane >> 4;
#pragma unroll
  for (int nj = 0; nj < NJ; ++nj) {
    const int colg = bx*BN + wc*(BN/2) + nj*16 + lcol;
    const float bv = bias[colg];
#pragma unroll
    for (int mi = 0; mi < 4; ++mi) {
      const int rowg = by*128 + wr*64 + mi*16 + lrq*4;
#pragma unroll
      for (int q = 0; q < 4; ++q) {
        float v = acc[mi][nj][q] + bv;
        if constexpr (ACT == 1) {
          float e = fexp2(-1.44269504f * fabsf(v));
          v = fmaxf(v, 0.f) + 0.69314718f * flog2(1.f + e);
        }
        if constexpr (OUT_BF16)
          ((unsigned short*)Cout)[(size_t)(rowg + q)*LDC + colg] = f2bf(v);
        else
          ((float*)Cout)[(size_t)(rowg + q)*LDC + colg] = v;
      }
    }
  }
}

// ---------------------------------------------------------------------------
// dbc partials: x @ W_x^T, K split 4 ways. grid (MT/64, 4).
// ---------------------------------------------------------------------------
__global__ __launch_bounds__(256) void dbc_mfma_kernel(
    const unsigned short* __restrict__ A,
    const unsigned short* __restrict__ Bw,
    float* __restrict__ partial)
{
  __shared__ unsigned short Abuf[64*32];
  __shared__ unsigned short Bbuf[96*32];

  const int tid  = threadIdx.x;
  const int lane = tid & 63;
  const int wid  = tid >> 6;
  const int lr    = lane >> 2;
  const int lslot = lane & 3;
  const size_t arow0 = (size_t)blockIdx.x * 64;
  const int ks   = blockIdx.y;
  const int k0b  = ks * (DI/4);

  f32x4 zero = {0.f, 0.f, 0.f, 0.f};
  f32x4 acc[6];
#pragma unroll
  for (int j = 0; j < 6; ++j) acc[j] = zero;

  for (int k0 = k0b; k0 < k0b + DI/4; k0 += 32) {
    {
      const int Rb = wid*16;
      const int r  = Rb + lr;
      const int c8 = lslot ^ ((r >> 1) & 3);
      const unsigned short* ga = A + (arow0 + r)*4096 + k0 + c8*8;
      __builtin_amdgcn_global_load_lds(
          (const __attribute__((address_space(1))) void*)ga,
          (__attribute__((address_space(3))) void*)(Abuf + Rb*32), 16, 0, 0);
    }
    if (wid < 3) {
#pragma unroll
      for (int i = 0; i < 2; ++i) {
        const int Rb = wid*32 + i*16;
        const int r  = Rb + lr;
        const int c8 = lslot ^ ((r >> 1) & 3);
        const unsigned short* gb = Bw + (size_t)r*DI + k0 + c8*8;
        __builtin_amdgcn_global_load_lds(
            (const __attribute__((address_space(1))) void*)gb,
            (__attribute__((address_space(3))) void*)(Bbuf + Rb*32), 16, 0, 0);
      }
    }
    __syncthreads();

    const int lrow = lane & 15, k8 = lane >> 4;
    const int ra = wid*16 + lrow;
    bf16x8 af = *(const bf16x8*)&Abuf[ra*32 + (k8 ^ ((ra >> 1) & 3))*8];
#pragma unroll
    for (int nj = 0; nj < 6; ++nj) {
      const int rb = nj*16 + lrow;
      bf16x8 bf_ = *(const bf16x8*)&Bbuf[rb*32 + (k8 ^ ((rb >> 1) & 3))*8];
      acc[nj] = __builtin_amdgcn_mfma_f32_16x16x32_bf16(af, bf_, acc[nj], 0, 0, 0);
    }
    __syncthreads();
  }

  const int lcol = lane & 15, lrq = lane >> 4;
  const int rowg = (int)arow0 + wid*16 + lrq*4;
#pragma unroll
  for (int nj = 0; nj < 6; ++nj) {
    const int colg = nj*16 + lcol;
#pragma unroll
    for (int q = 0; q < 4; ++q)
      partial[((size_t)ks*MT + rowg + q)*96 + colg] = acc[nj][q];
  }
}

// ---------------------------------------------------------------------------
__global__ __launch_bounds__(256) void dbc_reduce_kernel(
    const float* __restrict__ partial, const float* __restrict__ bx,
    float* __restrict__ dbc, unsigned short* __restrict__ draw_bf)
{
  const int gid = blockIdx.x*256 + threadIdx.x;
  const int m = gid / 96;
  const int c = gid - m*96;
  const size_t stride = (size_t)MT*96;
  float s = partial[gid] + partial[gid + stride]
          + partial[gid + 2*stride] + partial[gid + 3*stride] + bx[c];
  if (c < 64) draw_bf[(size_t)m*64 + c] = f2bf(s);
  else        dbc[(size_t)m*96 + c] = s;
}

// ---------------------------------------------------------------------------
// Chunked scan, pass A.  B rows staged in LDS.
// ---------------------------------------------------------------------------
__global__ __launch_bounds__(256) void scanA_kernel(
    const unsigned short* __restrict__ uib,
    const float* __restrict__ dbc,
    const unsigned short* __restrict__ delta_bf,
    const float* __restrict__ A2tab,
    float* __restrict__ P,
    float* __restrict__ S)
{
  __shared__ float Bsh[LCH][16];   // 2 KiB
  const int bid = blockIdx.x;
  const int d   = (bid & 7)*256 + threadIdx.x;
  const int c   = (bid >> 3) & (CHK-1);
  const int b   = bid >> 9;
  const int t0  = c * LCH;

  {
    int i = threadIdx.x;
    if (i < LCH*4) {
      int st = i >> 2, p = i & 3;
      float4 v = *(const float4*)(dbc + ((size_t)b*SEQ + t0 + st)*96 + 64 + p*4);
      *(float4*)&Bsh[st][p*4] = v;
    }
  }

  float A2[NST];
  {
    const float4* ap = (const float4*)(A2tab + (size_t)d*NST);
#pragma unroll
    for (int q = 0; q < 4; ++q) {
      float4 v = ap[q];
      A2[q*4+0] = v.x; A2[q*4+1] = v.y; A2[q*4+2] = v.z; A2[q*4+3] = v.w;
    }
  }

  float h[NST];
#pragma unroll
  for (int nn = 0; nn < NST; ++nn) h[nn] = 0.f;
  float sdt = 0.f;

  const unsigned short* dptr = delta_bf + ((size_t)b*SEQ + t0)*DI + d;
  const unsigned short* xptr = uib      + ((size_t)b*SEQ + t0)*4096 + d;

  float dt = bf2f(dptr[0]);
  float xv = bf2f(xptr[0]);
  __syncthreads();

  for (int t = 0; t < LCH; ++t) {
    const float dtc = dt, xvc = xv;
    if (t + 1 < LCH) {
      const size_t tn = (size_t)(t+1);
      dt = bf2f(dptr[tn*DI]);
      xv = bf2f(xptr[tn*4096]);
    }
    float4 Bv0 = *(const float4*)&Bsh[t][0];
    float4 Bv1 = *(const float4*)&Bsh[t][4];
    float4 Bv2 = *(const float4*)&Bsh[t][8];
    float4 Bv3 = *(const float4*)&Bsh[t][12];
    float Bc[NST] = {Bv0.x,Bv0.y,Bv0.z,Bv0.w, Bv1.x,Bv1.y,Bv1.z,Bv1.w,
                     Bv2.x,Bv2.y,Bv2.z,Bv2.w, Bv3.x,Bv3.y,Bv3.z,Bv3.w};
    sdt += dtc;
    const float xdt = xvc * dtc;
#pragma unroll
    for (int nn = 0; nn < NST; ++nn) {
      float dA = fexp2(dtc * A2[nn]);
      h[nn] = h[nn]*dA + xdt*Bc[nn];
    }
  }

  float* Pp = P + (((size_t)b*CHK + c)*DI + d)*NST;
  float* Sp = S + (((size_t)b*CHK + c)*DI + d)*NST;
#pragma unroll
  for (int q = 0; q < 4; ++q) {
    float4 pv = { fexp2(A2[q*4+0]*sdt), fexp2(A2[q*4+1]*sdt),
                  fexp2(A2[q*4+2]*sdt), fexp2(A2[q*4+3]*sdt) };
    float4 sv = { h[q*4+0], h[q*4+1], h[q*4+2], h[q*4+3] };
    *(float4*)(Pp + q*4) = pv;
    *(float4*)(Sp + q*4) = sv;
  }
}

// ---------------------------------------------------------------------------
__global__ __launch_bounds__(256) void scanB_kernel(
    const float* __restrict__ P, float* __restrict__ S)
{
  const int gid = blockIdx.x*256 + threadIdx.x;
  const int n4 = gid & 3;
  const int d  = (gid >> 2) & (DI-1);
  const int b  = gid >> 13;

  float4 h = {0.f, 0.f, 0.f, 0.f};
  for (int c = 0; c < CHK; ++c) {
    const size_t idx = (((size_t)b*CHK + c)*DI + d)*NST + n4*4;
    float4 p = *(const float4*)(P + idx);
    float4 s = *(const float4*)(S + idx);
    *(float4*)(S + idx) = h;
    h.x = h.x*p.x + s.x;
    h.y = h.y*p.y + s.y;
    h.z = h.z*p.z + s.z;
    h.w = h.w*p.w + s.w;
  }
}

// ---------------------------------------------------------------------------
// Chunked scan, pass C.  B+C rows staged in LDS (4 KiB).
// ---------------------------------------------------------------------------
__global__ __launch_bounds__(256) void scanC_kernel(
    const unsigned short* __restrict__ uib,
    const float* __restrict__ dbc,
    const unsigned short* __restrict__ delta_bf,
    const float* __restrict__ A2tab,
    const float* __restrict__ Dp,
    const float* __restrict__ S,
    unsigned short* __restrict__ y_bf)
{
  __shared__ float BCs[LCH][32];   // 4 KiB: [t][0..15]=B, [t][16..31]=C
  const int bid = blockIdx.x;
  const int d   = (bid & 7)*256 + threadIdx.x;
  const int c   = (bid >> 3) & (CHK-1);
  const int b   = bid >> 9;
  const int t0  = c * LCH;

  {
    int i = threadIdx.x;
    int st = i >> 3, p = i & 7;
    float4 v = *(const float4*)(dbc + ((size_t)b*SEQ + t0 + st)*96 + 64 + p*4);
    *(float4*)&BCs[st][p*4] = v;
  }

  float A2[NST];
  {
    const float4* ap = (const float4*)(A2tab + (size_t)d*NST);
#pragma unroll
    for (int q = 0; q < 4; ++q) {
      float4 v = ap[q];
      A2[q*4+0] = v.x; A2[q*4+1] = v.y; A2[q*4+2] = v.z; A2[q*4+3] = v.w;
    }
  }
  const float Dv = Dp[d];

  float h[NST];
  {
    const float* Sp = S + (((size_t)b*CHK + c)*DI + d)*NST;
#pragma unroll
    for (int q = 0; q < 4; ++q) {
      float4 sv = *(const float4*)(Sp + q*4);
      h[q*4+0] = sv.x; h[q*4+1] = sv.y; h[q*4+2] = sv.z; h[q*4+3] = sv.w;
    }
  }

  const unsigned short* dptr = delta_bf + ((size_t)b*SEQ + t0)*DI + d;
  const unsigned short* xptr = uib      + ((size_t)b*SEQ + t0)*4096 + d;
  unsigned short* yp         = y_bf     + ((size_t)b*SEQ + t0)*DI + d;

  float dt = bf2f(dptr[0]);
  float xv = bf2f(xptr[0]);
  float zv = bf2f(xptr[2048]);
  __syncthreads();

  for (int t = 0; t < LCH; ++t) {
    const float dtc = dt, xvc = xv, zvc = zv;
    if (t + 1 < LCH) {
      const size_t tn = (size_t)(t+1);
      dt = bf2f(dptr[tn*DI]);
      xv = bf2f(xptr[tn*4096]);
      zv = bf2f(xptr[tn*4096 + 2048]);
    }
    float4 Bv0 = *(const float4*)&BCs[t][0];
    float4 Bv1 = *(const float4*)&BCs[t][4];
    float4 Bv2 = *(const float4*)&BCs[t][8];
    float4 Bv3 = *(const float4*)&BCs[t][12];
    float4 Cv0 = *(const float4*)&BCs[t][16];
    float4 Cv1 = *(const float4*)&BCs[t][20];
    float4 Cv2 = *(const float4*)&BCs[t][24];
    float4 Cv3 = *(const float4*)&BCs[t][28];
    float Bc[NST] = {Bv0.x,Bv0.y,Bv0.z,Bv0.w, Bv1.x,Bv1.y,Bv1.z,Bv1.w,
                     Bv2.x,Bv2.y,Bv2.z,Bv2.w, Bv3.x,Bv3.y,Bv3.z,Bv3.w};
    float Cc[NST] = {Cv0.x,Cv0.y,Cv0.z,Cv0.w, Cv1.x,Cv1.y,Cv1.z,Cv1.w,
                     Cv2.x,Cv2.y,Cv2.z,Cv2.w, Cv3.x,Cv3.y,Cv3.z,Cv3.w};
    const float xdt = xvc * dtc;
    float y = 0.f;
#pragma unroll
    for (int nn = 0; nn < NST; ++nn) {
      float dA = fexp2(dtc * A2[nn]);
      h[nn] = h[nn]*dA + xdt*Bc[nn];
      y += h[nn]*Cc[nn];
    }
    y += xvc * Dv;
    y *= zvc / (1.f + fexp2(-1.44269504f * zvc));
    yp[(size_t)t*DI] = f2bf(y);
  }
}

// ---------------------------------------------------------------------------
extern "C" void kernel_launch(void* const* d_in, const int* in_sizes, int n_in,
                              void* d_out, int out_size, void* d_ws, size_t ws_size,
                              hipStream_t stream)
{
  const float* u     = (const float*)d_in[0];
  const float* W_in  = (const float*)d_in[1];
  const float* b_in  = (const float*)d_in[2];
  const float* W_x   = (const float*)d_in[3];
  const float* b_x   = (const float*)d_in[4];
  const float* W_dt  = (const float*)d_in[5];
  const float* b_dt  = (const float*)d_in[6];
  const float* A_log = (const float*)d_in[7];
  const float* Dp    = (const float*)d_in[8];
  const float* W_out = (const float*)d_in[9];
  const float* b_out = (const float*)d_in[10];
  float* out = (float*)d_out;

  unsigned short* ui_bf    = (unsigned short*)d_ws;
  float*          dbc      = (float*)(ui_bf + (size_t)MT*4096);
  unsigned short* delta_bf = (unsigned short*)(dbc + (size_t)MT*96);
  unsigned short* y_bf     = delta_bf + (size_t)MT*DI;
  unsigned short* wout_bf  = y_bf + (size_t)MT*DI;
  unsigned short* wx_bf    = wout_bf + (size_t)DM*DI;
  unsigned short* wdt_bf   = wx_bf + (size_t)96*DI;
  unsigned short* draw_bf  = wdt_bf + (size_t)DI*64;
  float*          S        = (float*)(draw_bf + (size_t)MT*64);
  float*          A2tab    = S + (size_t)BATCH*CHK*DI*NST;
  float*          partial  = A2tab + (size_t)DI*NST;

  unsigned short* u_bf   = (unsigned short*)d_out;
  unsigned short* win_bf = u_bf + (size_t)MT*DM;
  float* P = (float*)d_out;

  // 0) conversions + A2 table
  convall_kernel<<<CUM5/256, 256, 0, stream>>>(
      u, W_in, W_out, W_x, W_dt, A_log,
      u_bf, win_bf, wout_bf, wx_bf, wdt_bf, A2tab);

  // 1) ui = u @ W_in^T + b_in  — consume-one-phase-later 256^2 pipeline
  //    (128 KiB dynamic LDS); fall back to 2-phase kernel if not grantable.
  bool big = hipFuncSetAttribute(
      (const void*)gemm3_kernel<DM>,
      hipFuncAttributeMaxDynamicSharedMemorySize, 131072) == hipSuccess;
  if (big) {
    gemm3_kernel<DM><<<16*16, 512, 131072, stream>>>(
        u_bf, win_bf, b_in, ui_bf, 16);
  } else {
    gemm2_kernel<128, 32, true, 4096, 0><<<32*32, 256, 0, stream>>>(
        u_bf, win_bf, b_in, ui_bf, DM, 32);
  }

  // 2) dbc partials (K-split x4) + reduce
  dbc_mfma_kernel<<<dim3(MT/64, 4), 256, 0, stream>>>(ui_bf, wx_bf, partial);
  dbc_reduce_kernel<<<MT*96/256, 256, 0, stream>>>(partial, b_x, dbc, draw_bf);

  // 3) delta = softplus(draw @ W_dt^T + b_dt)
  gemm2_kernel<128, 32, true, 2048, 1><<<16*32, 256, 0, stream>>>(
      draw_bf, wdt_bf, b_dt, delta_bf, 64, 16);

  // 4) chunk-parallel selective scan (LDS-staged B/C panels)
  scanA_kernel<<<BATCH*CHK*DI/256, 256, 0, stream>>>(ui_bf, dbc, delta_bf, A2tab, P, S);
  scanB_kernel<<<BATCH*DI*4/256, 256, 0, stream>>>(P, S);
  scanC_kernel<<<BATCH*CHK*DI/256, 256, 0, stream>>>(ui_bf, dbc, delta_bf, A2tab, Dp, S, y_bf);

  // 5) out = y @ W_out^T + b_out — direct (round-8 proven config)
  gemm2_kernel<64, 64, false, 1024, 0><<<16*32, 256, 0, stream>>>(
      y_bf, wout_bf, b_out, out, DI, 16);
}